// Round 1
// baseline (635.618 us; speedup 1.0000x reference)
//
#include <hip/hip_runtime.h>
#include <math.h>

// Problem constants (b=2, c=32, H=W=256, 256 superpixels, R=1, 5 iters, tau=0.01)
#define Bn 2
#define Cn 32
#define Hn 256
#define Wn 256
#define HSn 16          // superpixel grid rows
#define WSn 16          // superpixel grid cols
#define NCELL 256       // HSn*WSn
#define WINn 48         // 3*sh
#define NPn 2304        // 48*48 neighborhood pixels per cell
#define TAUf 0.01f

// ---------------------------------------------------------------------------
// prep: per-pixel L2-normalize x along channels, write channel-last xn[b][y][x][c]
// ---------------------------------------------------------------------------
__global__ __launch_bounds__(256) void prep_kernel(const float* __restrict__ x,
                                                   float* __restrict__ xn) {
    int idx = blockIdx.x * 256 + threadIdx.x;   // 0 .. B*H*W-1
    int b = idx >> 16;                          // H*W = 65536
    int rem = idx & 65535;
    const float* xb = x + (size_t)b * (Cn * 65536);
    float v[32];
    float ss = 0.f;
#pragma unroll
    for (int c = 0; c < 32; ++c) {
        float t = xb[c * 65536 + rem];
        v[c] = t;
        ss += t * t;
    }
    float rn = 1.0f / sqrtf(ss);
    float4* out = (float4*)(xn + (size_t)idx * 32);
#pragma unroll
    for (int q = 0; q < 8; ++q) {
        out[q] = make_float4(v[4*q]*rn, v[4*q+1]*rn, v[4*q+2]*rn, v[4*q+3]*rn);
    }
}

// ---------------------------------------------------------------------------
// init_clst: block-mean of RAW x over each 16x16 block, then L2-normalize.
// clst layout: [b][cell][c] (c contiguous)
// ---------------------------------------------------------------------------
__global__ __launch_bounds__(256) void init_clst_kernel(const float* __restrict__ x,
                                                        float* __restrict__ clst) {
    int blk = blockIdx.x;          // b*256 + cell
    int b = blk >> 8;
    int cell = blk & 255;
    int ci = cell >> 4, cj = cell & 15;
    int t = threadIdx.x;
    int c = t >> 3;                // 0..31
    int g = t & 7;                 // 0..7

    const float* xb = x + ((size_t)b * 32 + c) * 65536;
    float s = 0.f;
    for (int k = 0; k < 32; ++k) {
        int pidx = g * 32 + k;           // 0..255 pixel within block
        int py = pidx >> 4, px = pidx & 15;
        s += xb[(ci * 16 + py) * 256 + (cj * 16 + px)];
    }
    __shared__ float red[256];
    __shared__ float smean[32];
    __shared__ float srn;
    red[t] = s;
    __syncthreads();
    if ((t & 7) < 4) red[t] += red[t + 4];
    __syncthreads();
    if ((t & 7) < 2) red[t] += red[t + 2];
    __syncthreads();
    if ((t & 7) == 0) smean[t >> 3] = (red[t] + red[t + 1]) * (1.0f / 256.0f);
    __syncthreads();
    if (t == 0) {
        float ss = 0.f;
        for (int cc = 0; cc < 32; ++cc) ss += smean[cc] * smean[cc];
        srn = 1.0f / sqrtf(ss);
    }
    __syncthreads();
    if (t < 32) clst[((size_t)b * NCELL + cell) * 32 + t] = smean[t] * srn;
}

// ---------------------------------------------------------------------------
// iter: one block per (b, cell). Compute sim over 48x48 window vs clst,
// softmax over 2304 (tau), weighted-mean new clst, L2-normalize.
// Optionally writes s2p (last iteration).
// ---------------------------------------------------------------------------
__global__ __launch_bounds__(256) void iter_kernel(const float* __restrict__ xn,
                                                   const float* __restrict__ clst_in,
                                                   float* __restrict__ clst_out,
                                                   float* __restrict__ s2p_out,
                                                   int write_s2p) {
    int blk = blockIdx.x;
    int b = blk >> 8;
    int cell = blk & 255;
    int ci = cell >> 4, cj = cell & 15;
    int t = threadIdx.x;

    __shared__ float sclst[32];
    __shared__ float w[NPn];      // 2304 floats
    __shared__ float red[256];
    __shared__ float racc[256];
    __shared__ float srn;

    if (t < 32) sclst[t] = clst_in[((size_t)b * NCELL + cell) * 32 + t];
    __syncthreads();

    int y0 = ci * 16 - 16;
    int x0 = cj * 16 - 16;

    float sims[9];
    float lmax = -INFINITY;
#pragma unroll
    for (int k = 0; k < 9; ++k) {
        int p = t + k * 256;
        int ky = p / 48, kx = p % 48;
        int y = y0 + ky, xx = x0 + kx;
        float s = 0.f;
        if (y >= 0 && y < 256 && xx >= 0 && xx < 256) {
            const float* f = xn + ((size_t)b * 65536 + y * 256 + xx) * 32;
#pragma unroll
            for (int c = 0; c < 32; ++c) s += f[c] * sclst[c];
        }
        if (s == 0.f) s = -INFINITY;   // reference masks sim==0 (zero padding)
        sims[k] = s;
        lmax = fmaxf(lmax, s);
    }

    // block max
    red[t] = lmax;
    __syncthreads();
    for (int st = 128; st > 0; st >>= 1) {
        if (t < st) red[t] = fmaxf(red[t], red[t + st]);
        __syncthreads();
    }
    float mx = red[0];
    __syncthreads();

    float lsum = 0.f;
#pragma unroll
    for (int k = 0; k < 9; ++k) {
        float e = (sims[k] == -INFINITY) ? 0.f : expf((sims[k] - mx) * (1.0f / TAUf));
        w[t + k * 256] = e;
        lsum += e;
    }
    red[t] = lsum;
    __syncthreads();
    for (int st = 128; st > 0; st >>= 1) {
        if (t < st) red[t] += red[t + st];
        __syncthreads();
    }
    float rsum = 1.0f / red[0];
    __syncthreads();

#pragma unroll
    for (int k = 0; k < 9; ++k) {
        float ww = w[t + k * 256] * rsum;
        w[t + k * 256] = ww;
        if (write_s2p) {
            // s2p layout (b, 2304, 16, 16)
            s2p_out[(((size_t)b * NPn + (t + k * 256)) * 16 + ci) * 16 + cj] = ww;
        }
    }
    __syncthreads();

    // phase 2: new clst accumulation. thread = (pixel-group pg, channel c)
    int c = t & 31;
    int pg = t >> 5;               // 0..7
    float acc = 0.f;
    for (int p = pg * 288; p < pg * 288 + 288; ++p) {
        float ww = w[p];
        if (ww != 0.f) {
            int ky = p / 48, kx = p % 48;
            int y = y0 + ky, xx = x0 + kx;
            acc += ww * xn[((size_t)b * 65536 + y * 256 + xx) * 32 + c];
        }
    }
    racc[t] = acc;
    __syncthreads();
    if (pg < 4) racc[t] += racc[t + 128];
    __syncthreads();
    if (pg < 2) racc[t] += racc[t + 64];
    __syncthreads();
    if (pg < 1) racc[t] += racc[t + 32];
    __syncthreads();
    if (t == 0) {
        float ss = 0.f;
        for (int cc = 0; cc < 32; ++cc) ss += racc[cc] * racc[cc];
        srn = 1.0f / sqrtf(ss);
    }
    __syncthreads();
    if (t < 32) clst_out[((size_t)b * NCELL + cell) * 32 + t] = racc[t] * srn;
}

// ---------------------------------------------------------------------------
// p2s: per pixel, dot vs 3x3 candidate clusters, softmax over 9.
// p2s layout (b, 9, H, W)
// ---------------------------------------------------------------------------
__global__ __launch_bounds__(256) void p2s_kernel(const float* __restrict__ xn,
                                                  const float* __restrict__ clst,
                                                  float* __restrict__ p2s) {
    int idx = blockIdx.x * 256 + threadIdx.x;  // B*H*W
    int b = idx >> 16;
    int rem = idx & 65535;
    int y = rem >> 8, xx = rem & 255;
    int i = y >> 4, j = xx >> 4;

    const float* f = xn + (size_t)idx * 32;
    float feat[32];
#pragma unroll
    for (int c = 0; c < 32; ++c) feat[c] = f[c];

    float l[9];
    float mx = -INFINITY;
#pragma unroll
    for (int q = 0; q < 9; ++q) {
        int qy = q / 3, qx = q % 3;
        int ci = i - 1 + qy, cj = j - 1 + qx;
        float s = 0.f;
        if (ci >= 0 && ci < 16 && cj >= 0 && cj < 16) {
            const float* cf = clst + ((size_t)b * NCELL + ci * 16 + cj) * 32;
#pragma unroll
            for (int c = 0; c < 32; ++c) s += feat[c] * cf[c];
        }
        l[q] = (s == 0.f) ? -INFINITY : s * (1.0f / TAUf);
        mx = fmaxf(mx, l[q]);
    }
    float e[9];
    float sum = 0.f;
#pragma unroll
    for (int q = 0; q < 9; ++q) {
        e[q] = (l[q] == -INFINITY) ? 0.f : expf(l[q] - mx);
        sum += e[q];
    }
    float rs = 1.0f / sum;
#pragma unroll
    for (int q = 0; q < 9; ++q) {
        p2s[((size_t)b * 9 + q) * 65536 + rem] = e[q] * rs;
    }
}

// ---------------------------------------------------------------------------
// clst output: transpose [b][cell][c] -> (b, c, 16, 16)
// ---------------------------------------------------------------------------
__global__ __launch_bounds__(256) void clst_out_kernel(const float* __restrict__ clst,
                                                       float* __restrict__ out) {
    int idx = blockIdx.x * 256 + threadIdx.x;  // 16384
    int b = idx >> 13;
    int r = idx & 8191;
    int c = r >> 8;
    int cell = r & 255;
    out[idx] = clst[((size_t)b * NCELL + cell) * 32 + c];
}

extern "C" void kernel_launch(void* const* d_in, const int* in_sizes, int n_in,
                              void* d_out, int out_size, void* d_ws, size_t ws_size,
                              hipStream_t stream) {
    const float* x = (const float*)d_in[0];
    float* out = (float*)d_out;

    float* out_clst = out;                       // 2*32*16*16      = 16384
    float* out_p2s  = out + 16384;               // 2*9*256*256     = 1179648
    float* out_s2p  = out + 16384 + 1179648;     // 2*2304*16*16    = 1179648

    float* ws = (float*)d_ws;
    float* xn    = ws;                           // 2*256*256*32 = 4194304 floats
    float* clstA = ws + 4194304;                 // 16384 floats
    float* clstB = clstA + 16384;                // 16384 floats

    prep_kernel<<<512, 256, 0, stream>>>(x, xn);
    init_clst_kernel<<<Bn * NCELL, 256, 0, stream>>>(x, clstA);

    float* cin = clstA;
    float* cout = clstB;
    for (int it = 0; it < 5; ++it) {
        iter_kernel<<<Bn * NCELL, 256, 0, stream>>>(xn, cin, cout, out_s2p,
                                                    (it == 4) ? 1 : 0);
        float* tmp = cin; cin = cout; cout = tmp;
    }
    // final clst is in `cin`
    p2s_kernel<<<512, 256, 0, stream>>>(xn, cin, out_p2s);
    clst_out_kernel<<<64, 256, 0, stream>>>(cin, out_clst);
}

// Round 2
// 248.041 us; speedup vs baseline: 2.5626x; 2.5626x over previous
//
#include <hip/hip_runtime.h>
#include <math.h>

// Problem constants (b=2, c=32, H=W=256, 256 superpixels, R=1, 5 iters, tau=0.01)
#define TAU_INV 100.0f

// ---------------------------------------------------------------------------
// prep: per-pixel L2-normalize x along channels, write channel-last xn[b][y][x][c]
// ---------------------------------------------------------------------------
__global__ __launch_bounds__(256) void prep_kernel(const float* __restrict__ x,
                                                   float* __restrict__ xn) {
    int idx = blockIdx.x * 256 + threadIdx.x;   // 0 .. B*H*W-1
    int b = idx >> 16;                          // H*W = 65536
    int rem = idx & 65535;
    const float* xb = x + (size_t)b * (32 * 65536);
    float v[32];
    float ss = 0.f;
#pragma unroll
    for (int c = 0; c < 32; ++c) {
        float t = xb[c * 65536 + rem];
        v[c] = t;
        ss += t * t;
    }
    float rn = 1.0f / sqrtf(ss);
    float4* out = (float4*)(xn + (size_t)idx * 32);
#pragma unroll
    for (int q = 0; q < 8; ++q) {
        out[q] = make_float4(v[4*q]*rn, v[4*q+1]*rn, v[4*q+2]*rn, v[4*q+3]*rn);
    }
}

// ---------------------------------------------------------------------------
// init_clst: block-mean of RAW x over each 16x16 block, then L2-normalize.
// clst layout: [b][cell][c] (c contiguous)
// ---------------------------------------------------------------------------
__global__ __launch_bounds__(256) void init_clst_kernel(const float* __restrict__ x,
                                                        float* __restrict__ clst) {
    int blk = blockIdx.x;          // b*256 + cell
    int b = blk >> 8;
    int cell = blk & 255;
    int ci = cell >> 4, cj = cell & 15;
    int t = threadIdx.x;
    int c = t >> 3;                // 0..31
    int g = t & 7;                 // 0..7

    const float* xb = x + ((size_t)b * 32 + c) * 65536;
    float s = 0.f;
    for (int k = 0; k < 32; ++k) {
        int pidx = g * 32 + k;           // 0..255 pixel within block
        int py = pidx >> 4, px = pidx & 15;
        s += xb[(ci * 16 + py) * 256 + (cj * 16 + px)];
    }
    __shared__ float red[256];
    __shared__ float smean[32];
    __shared__ float srn;
    red[t] = s;
    __syncthreads();
    if ((t & 7) < 4) red[t] += red[t + 4];
    __syncthreads();
    if ((t & 7) < 2) red[t] += red[t + 2];
    __syncthreads();
    if ((t & 7) == 0) smean[t >> 3] = (red[t] + red[t + 1]) * (1.0f / 256.0f);
    __syncthreads();
    if (t == 0) {
        float ss = 0.f;
        for (int cc = 0; cc < 32; ++cc) ss += smean[cc] * smean[cc];
        srn = 1.0f / sqrtf(ss);
    }
    __syncthreads();
    if (t < 32) clst[((size_t)b * 256 + cell) * 32 + t] = smean[t] * srn;
}

// ---------------------------------------------------------------------------
// pm: per (b, pixel-block): max over the block's 256 pixels of dot(x, clst_q)
// for each of the 9 neighbor cells q. pm[b][blk][q].
// ---------------------------------------------------------------------------
__global__ __launch_bounds__(256) void pm_kernel(const float* __restrict__ xn,
                                                 const float* __restrict__ clst,
                                                 float* __restrict__ pm) {
    int blk = blockIdx.x;           // b*256 + block
    int b = blk >> 8;
    int cell = blk & 255;
    int bi = cell >> 4, bj = cell & 15;
    int t = threadIdx.x;
    __shared__ float sclst[9][32];
    __shared__ float pmw[4][9];

    for (int u = t; u < 288; u += 256) {
        int q = u >> 5, c = u & 31;
        int ii = bi + q / 3 - 1, jj = bj + q % 3 - 1;
        float v = 0.f;
        if (ii >= 0 && ii < 16 && jj >= 0 && jj < 16)
            v = clst[((size_t)(b * 256 + ii * 16 + jj)) * 32 + c];
        sclst[q][c] = v;
    }
    __syncthreads();

    int y = bi * 16 + (t >> 4), xx = bj * 16 + (t & 15);
    const float4* f4 = (const float4*)(xn + ((size_t)(b * 65536 + y * 256 + xx)) * 32);
    float fv[32];
#pragma unroll
    for (int q = 0; q < 8; ++q) {
        float4 v = f4[q];
        fv[4*q] = v.x; fv[4*q+1] = v.y; fv[4*q+2] = v.z; fv[4*q+3] = v.w;
    }

    int wid = t >> 6, lane = t & 63;
#pragma unroll
    for (int q = 0; q < 9; ++q) {
        float s = 0.f;
#pragma unroll
        for (int c = 0; c < 32; ++c) s += fv[c] * sclst[q][c];
#pragma unroll
        for (int k = 32; k >= 1; k >>= 1) s = fmaxf(s, __shfl_xor(s, k));
        if (lane == 0) pmw[wid][q] = s;
    }
    __syncthreads();
    if (t < 9) {
        float m = fmaxf(fmaxf(pmw[0][t], pmw[1][t]), fmaxf(pmw[2][t], pmw[3][t]));
        pm[blk * 9 + t] = m;
    }
}

// ---------------------------------------------------------------------------
// accum: one block per (b, pixel-block, q). Target cell (i,j)=(bi+qy-1, bj+qx-1).
// Recompute the 256 dots vs that cell, e=exp((d-m_cell)/tau), accumulate
// partial S[b][blk][q][c] = sum_p e_p * x_p[c] and denp[b][blk][q] = sum e.
// ---------------------------------------------------------------------------
__global__ __launch_bounds__(256) void accum_kernel(const float* __restrict__ xn,
                                                    const float* __restrict__ clst,
                                                    const float* __restrict__ pm,
                                                    float* __restrict__ S,
                                                    float* __restrict__ denp) {
    int gid = blockIdx.x;            // b*2304 + blk*9 + q
    int q = gid % 9;
    int blkc = (gid / 9) & 255;
    int b = gid / 2304;
    int bi = blkc >> 4, bj = blkc & 15;
    int i = bi + q / 3 - 1, j = bj + q % 3 - 1;
    if (i < 0 || i > 15 || j < 0 || j > 15) return;   // dead pair, whole block exits
    int t = threadIdx.x;

    __shared__ float sclst[32];
    __shared__ float se[256];
    __shared__ float red[256];
    __shared__ float gm[9];
    __shared__ float sm;

    if (t < 32) sclst[t] = clst[((size_t)(b * 256 + i * 16 + j)) * 32 + t];
    if (t >= 64 && t < 73) {
        int u = t - 64;
        int oy = u / 3 - 1, ox = u % 3 - 1;
        int ii = i + oy, jj = j + ox;
        float v = -INFINITY;
        if (ii >= 0 && ii < 16 && jj >= 0 && jj < 16)
            v = pm[((b * 256 + ii * 16 + jj) * 9) + (1 - oy) * 3 + (1 - ox)];
        gm[u] = v;
    }
    __syncthreads();
    if (t == 0) {
        float m = gm[0];
        for (int u = 1; u < 9; ++u) m = fmaxf(m, gm[u]);
        sm = m;
    }
    // dot for my pixel (overlaps with t==0's small loop; visibility via next sync)
    const float* f = xn + ((size_t)(b * 65536 + (bi * 16 + (t >> 4)) * 256 + bj * 16 + (t & 15))) * 32;
    float s = 0.f;
#pragma unroll
    for (int c = 0; c < 32; ++c) s += f[c] * sclst[c];
    __syncthreads();
    float e = (s == 0.f) ? 0.f : expf((s - sm) * TAU_INV);
    se[t] = e;
    __syncthreads();

    // accumulate: thread = (c = t&31, pg = t>>5), 32 pixels each
    int c = t & 31, pg = t >> 5;
    const float* base = xn + ((size_t)(b * 65536 + bi * 16 * 256 + bj * 16)) * 32;
    float acc = 0.f;
#pragma unroll
    for (int k = 0; k < 32; ++k) {
        int p = pg * 32 + k;
        acc = fmaf(se[p], base[(size_t)(p >> 4) * 8192 + (p & 15) * 32 + c], acc);
    }
    red[t] = acc;
    __syncthreads();
    if (t < 128) red[t] += red[t + 128];
    __syncthreads();
    if (t < 64) red[t] += red[t + 64];
    __syncthreads();
    if (t < 32) S[(size_t)gid * 32 + t] = red[t] + red[t + 32];
    // denominator partial: one wave sums se
    if (t < 64) {
        float d2 = se[t] + se[t + 64] + se[t + 128] + se[t + 192];
#pragma unroll
        for (int k = 32; k >= 1; k >>= 1) d2 += __shfl_xor(d2, k);
        if (t == 0) denp[gid] = d2;
    }
}

// ---------------------------------------------------------------------------
// combine: per (b,cell,c): sum the 9 neighbor partials, L2-normalize.
// Optionally also sum the 9 den partials -> dcell (last iteration).
// ---------------------------------------------------------------------------
__global__ __launch_bounds__(256) void combine_kernel(const float* __restrict__ S,
                                                      const float* __restrict__ denp,
                                                      float* __restrict__ clst_out,
                                                      float* __restrict__ dcell,
                                                      int compute_den) {
    int t = threadIdx.x;
    int cellIdx = blockIdx.x * 8 + (t >> 5);  // 0..511
    int b = cellIdx >> 8;
    int cell = cellIdx & 255;
    int i = cell >> 4, j = cell & 15;
    int c = t & 31;
    float acc = 0.f;
#pragma unroll
    for (int u = 0; u < 9; ++u) {
        int oy = u / 3 - 1, ox = u % 3 - 1;
        int ii = i + oy, jj = j + ox;
        if (ii >= 0 && ii < 16 && jj >= 0 && jj < 16) {
            int src = ((b * 256 + ii * 16 + jj) * 9) + (1 - oy) * 3 + (1 - ox);
            acc += S[(size_t)src * 32 + c];
        }
    }
    float ss = acc * acc;
#pragma unroll
    for (int k = 16; k >= 1; k >>= 1) ss += __shfl_xor(ss, k);  // within 32-lane group
    float rn = 1.0f / sqrtf(ss);
    clst_out[(size_t)cellIdx * 32 + c] = acc * rn;
    if (compute_den && c == 0) {
        float dsum = 0.f;
        for (int u = 0; u < 9; ++u) {
            int oy = u / 3 - 1, ox = u % 3 - 1;
            int ii = i + oy, jj = j + ox;
            if (ii >= 0 && ii < 16 && jj >= 0 && jj < 16)
                dsum += denp[((b * 256 + ii * 16 + jj) * 9) + (1 - oy) * 3 + (1 - ox)];
        }
        dcell[cellIdx] = dsum;
    }
}

// ---------------------------------------------------------------------------
// s2p (last iteration): per (b, pixel-block), recompute e for the 9 targets
// and write normalized weights at window positions. Padded entries are
// pre-zeroed by a memset in kernel_launch.
// s2p layout (b, 2304, 16, 16); clst here is the iteration-4 input clst.
// ---------------------------------------------------------------------------
__global__ __launch_bounds__(256) void s2p_kernel(const float* __restrict__ xn,
                                                  const float* __restrict__ clst,
                                                  const float* __restrict__ pm,
                                                  const float* __restrict__ dcell,
                                                  float* __restrict__ s2p) {
    int blk = blockIdx.x;
    int b = blk >> 8;
    int cell = blk & 255;
    int bi = cell >> 4, bj = cell & 15;
    int t = threadIdx.x;
    __shared__ float sclst[9][32];
    __shared__ float smq[9];
    __shared__ float srdn[9];

    for (int u = t; u < 288; u += 256) {
        int q = u >> 5, c = u & 31;
        int ii = bi + q / 3 - 1, jj = bj + q % 3 - 1;
        float v = 0.f;
        if (ii >= 0 && ii < 16 && jj >= 0 && jj < 16)
            v = clst[((size_t)(b * 256 + ii * 16 + jj)) * 32 + c];
        sclst[q][c] = v;
    }
    if (t < 9) {
        int i = bi + t / 3 - 1, j = bj + t % 3 - 1;
        float m = -INFINITY;
        float rd = 0.f;
        if (i >= 0 && i < 16 && j >= 0 && j < 16) {
            for (int u = 0; u < 9; ++u) {
                int ii = i + u / 3 - 1, jj = j + u % 3 - 1;
                if (ii >= 0 && ii < 16 && jj >= 0 && jj < 16)
                    m = fmaxf(m, pm[((b * 256 + ii * 16 + jj) * 9) + (2 - u / 3) * 3 + (2 - u % 3)]);
            }
            rd = 1.0f / dcell[b * 256 + i * 16 + j];
        }
        smq[t] = m;
        srdn[t] = rd;
    }
    __syncthreads();

    int ry = t >> 4, rx = t & 15;
    const float4* f4 = (const float4*)(xn + ((size_t)(b * 65536 + (bi * 16 + ry) * 256 + bj * 16 + rx)) * 32);
    float fv[32];
#pragma unroll
    for (int q = 0; q < 8; ++q) {
        float4 v = f4[q];
        fv[4*q] = v.x; fv[4*q+1] = v.y; fv[4*q+2] = v.z; fv[4*q+3] = v.w;
    }

#pragma unroll
    for (int q = 0; q < 9; ++q) {
        int qy = q / 3, qx = q % 3;
        int i = bi + qy - 1, j = bj + qx - 1;
        if (i < 0 || i > 15 || j < 0 || j > 15) continue;
        float s = 0.f;
#pragma unroll
        for (int c = 0; c < 32; ++c) s += fv[c] * sclst[q][c];
        float e = (s == 0.f) ? 0.f : expf((s - smq[q]) * TAU_INV);
        int p = (ry + 16 * (2 - qy)) * 48 + rx + 16 * (2 - qx);
        s2p[((size_t)(b * 2304 + p)) * 256 + i * 16 + j] = e * srdn[q];
    }
}

// ---------------------------------------------------------------------------
// p2s: per pixel, dot vs 3x3 candidate clusters, softmax over 9. (b, 9, H, W)
// ---------------------------------------------------------------------------
__global__ __launch_bounds__(256) void p2s_kernel(const float* __restrict__ xn,
                                                  const float* __restrict__ clst,
                                                  float* __restrict__ p2s) {
    int idx = blockIdx.x * 256 + threadIdx.x;  // B*H*W
    int b = idx >> 16;
    int rem = idx & 65535;
    int y = rem >> 8, xx = rem & 255;
    int i = y >> 4, j = xx >> 4;

    const float* f = xn + (size_t)idx * 32;
    float feat[32];
#pragma unroll
    for (int c = 0; c < 32; ++c) feat[c] = f[c];

    float l[9];
    float mx = -INFINITY;
#pragma unroll
    for (int q = 0; q < 9; ++q) {
        int qy = q / 3, qx = q % 3;
        int ci = i - 1 + qy, cj = j - 1 + qx;
        float s = 0.f;
        if (ci >= 0 && ci < 16 && cj >= 0 && cj < 16) {
            const float* cf = clst + ((size_t)b * 256 + ci * 16 + cj) * 32;
#pragma unroll
            for (int c = 0; c < 32; ++c) s += feat[c] * cf[c];
        }
        l[q] = (s == 0.f) ? -INFINITY : s * TAU_INV;
        mx = fmaxf(mx, l[q]);
    }
    float e[9];
    float sum = 0.f;
#pragma unroll
    for (int q = 0; q < 9; ++q) {
        e[q] = (l[q] == -INFINITY) ? 0.f : expf(l[q] - mx);
        sum += e[q];
    }
    float rs = 1.0f / sum;
#pragma unroll
    for (int q = 0; q < 9; ++q) {
        p2s[((size_t)b * 9 + q) * 65536 + rem] = e[q] * rs;
    }
}

// ---------------------------------------------------------------------------
// clst output: transpose [b][cell][c] -> (b, c, 16, 16)
// ---------------------------------------------------------------------------
__global__ __launch_bounds__(256) void clst_out_kernel(const float* __restrict__ clst,
                                                       float* __restrict__ out) {
    int idx = blockIdx.x * 256 + threadIdx.x;  // 16384
    int b = idx >> 13;
    int r = idx & 8191;
    int c = r >> 8;
    int cell = r & 255;
    out[idx] = clst[((size_t)b * 256 + cell) * 32 + c];
}

extern "C" void kernel_launch(void* const* d_in, const int* in_sizes, int n_in,
                              void* d_out, int out_size, void* d_ws, size_t ws_size,
                              hipStream_t stream) {
    const float* x = (const float*)d_in[0];
    float* out = (float*)d_out;

    float* out_clst = out;                       // 2*32*16*16      = 16384
    float* out_p2s  = out + 16384;               // 2*9*256*256     = 1179648
    float* out_s2p  = out + 16384 + 1179648;     // 2*2304*16*16    = 1179648

    float* ws = (float*)d_ws;
    float* xn    = ws;                           // 4,194,304 floats
    float* clstA = xn + 4194304;                 // 16,384
    float* clstB = clstA + 16384;                // 16,384
    float* pm    = clstB + 16384;                // 4,608
    float* S     = pm + 4608;                    // 147,456
    float* denp  = S + 147456;                   // 4,608
    float* dcell = denp + 4608;                  // 512
    // total ~17.6 MB

    prep_kernel<<<512, 256, 0, stream>>>(x, xn);
    init_clst_kernel<<<512, 256, 0, stream>>>(x, clstA);

    // zero the s2p output region: padded window positions are never written
    // by s2p_kernel but must be exactly 0 (reference softmax of -inf).
    hipMemsetAsync(out_s2p, 0, (size_t)1179648 * sizeof(float), stream);

    float* cin = clstA;
    float* cout = clstB;
    for (int it = 0; it < 5; ++it) {
        pm_kernel<<<512, 256, 0, stream>>>(xn, cin, pm);
        accum_kernel<<<4608, 256, 0, stream>>>(xn, cin, pm, S, denp);
        combine_kernel<<<64, 256, 0, stream>>>(S, denp, cout, dcell, (it == 4) ? 1 : 0);
        float* tmp = cin; cin = cout; cout = tmp;
    }
    // cin = final clst (after 5 updates); cout = clst input of iteration 5
    s2p_kernel<<<512, 256, 0, stream>>>(xn, cout, pm, dcell, out_s2p);
    p2s_kernel<<<512, 256, 0, stream>>>(xn, cin, out_p2s);
    clst_out_kernel<<<64, 256, 0, stream>>>(cin, out_clst);
}

// Round 3
// 170.576 us; speedup vs baseline: 3.7263x; 1.4541x over previous
//
#include <hip/hip_runtime.h>
#include <math.h>

// Problem constants (b=2, c=32, H=W=256, 256 superpixels, R=1, 5 iters, tau=0.01)
#define TAU_INV 100.0f

// ---------------------------------------------------------------------------
// prep_init: one block per (b, 16x16 pixel block).
//  - per-pixel L2-normalize x along channels -> xn[b][y][x][c] (channel-last)
//  - raw block mean over the 16x16 block, L2-normalized -> clst[b][cell][c]
// ---------------------------------------------------------------------------
__global__ __launch_bounds__(256) void prep_init_kernel(const float* __restrict__ x,
                                                        float* __restrict__ xn,
                                                        float* __restrict__ clst) {
    int blk = blockIdx.x;          // b*256 + cell
    int b = blk >> 8;
    int cell = blk & 255;
    int ci = cell >> 4, cj = cell & 15;
    int t = threadIdx.x;
    int py = t >> 4, px = t & 15;
    int y = ci * 16 + py, xx = cj * 16 + px;
    int rem = y * 256 + xx;

    __shared__ float sraw[256 * 33];   // padded stride 33
    __shared__ float red[256];

    const float* xb = x + (size_t)b * (32 * 65536);
    float v[32];
    float ss = 0.f;
#pragma unroll
    for (int c = 0; c < 32; ++c) {
        float tv = xb[c * 65536 + rem];
        v[c] = tv;
        ss += tv * tv;
        sraw[t * 33 + c] = tv;
    }
    float rn = 1.0f / sqrtf(ss);
    float4* outp = (float4*)(xn + ((size_t)b * 65536 + rem) * 32);
#pragma unroll
    for (int q = 0; q < 8; ++q)
        outp[q] = make_float4(v[4*q]*rn, v[4*q+1]*rn, v[4*q+2]*rn, v[4*q+3]*rn);

    __syncthreads();
    // per-channel sum over 256 pixels: thread = (c = t&31, pg = t>>5)
    int c = t & 31, pg = t >> 5;
    float acc = 0.f;
#pragma unroll
    for (int k = 0; k < 32; ++k) acc += sraw[(pg * 32 + k) * 33 + c];
    red[t] = acc;
    __syncthreads();
    if (t < 128) red[t] += red[t + 128];
    __syncthreads();
    if (t < 64) red[t] += red[t + 64];
    __syncthreads();
    if (t < 32) {
        float m = (red[t] + red[t + 32]) * (1.0f / 256.0f);
        float p = m * m;
#pragma unroll
        for (int k = 16; k >= 1; k >>= 1) p += __shfl_xor(p, k);
        clst[(size_t)blk * 32 + t] = m * (1.0f / sqrtf(p));
    }
}

// ---------------------------------------------------------------------------
// pm: per (b, pixel-block): max over the block's 256 pixels of dot(x, clst_q)
// for each of the 9 neighbor cells q. pm[b][blk][q].
// ---------------------------------------------------------------------------
__global__ __launch_bounds__(256) void pm_kernel(const float* __restrict__ xn,
                                                 const float* __restrict__ clst,
                                                 float* __restrict__ pm) {
    int blk = blockIdx.x;           // b*256 + block
    int b = blk >> 8;
    int cell = blk & 255;
    int bi = cell >> 4, bj = cell & 15;
    int t = threadIdx.x;
    __shared__ float sclst[9][32];
    __shared__ float pmw[4][9];

    for (int u = t; u < 288; u += 256) {
        int q = u >> 5, c = u & 31;
        int ii = bi + q / 3 - 1, jj = bj + q % 3 - 1;
        float v = 0.f;
        if (ii >= 0 && ii < 16 && jj >= 0 && jj < 16)
            v = clst[((size_t)(b * 256 + ii * 16 + jj)) * 32 + c];
        sclst[q][c] = v;
    }
    __syncthreads();

    int y = bi * 16 + (t >> 4), xx = bj * 16 + (t & 15);
    const float4* f4 = (const float4*)(xn + ((size_t)(b * 65536 + y * 256 + xx)) * 32);
    float fv[32];
#pragma unroll
    for (int q = 0; q < 8; ++q) {
        float4 v = f4[q];
        fv[4*q] = v.x; fv[4*q+1] = v.y; fv[4*q+2] = v.z; fv[4*q+3] = v.w;
    }

    int wid = t >> 6, lane = t & 63;
#pragma unroll
    for (int q = 0; q < 9; ++q) {
        float s = 0.f;
#pragma unroll
        for (int c = 0; c < 32; ++c) s += fv[c] * sclst[q][c];
#pragma unroll
        for (int k = 32; k >= 1; k >>= 1) s = fmaxf(s, __shfl_xor(s, k));
        if (lane == 0) pmw[wid][q] = s;
    }
    __syncthreads();
    if (t < 9) {
        float m = fmaxf(fmaxf(pmw[0][t], pmw[1][t]), fmaxf(pmw[2][t], pmw[3][t]));
        pm[blk * 9 + t] = m;
    }
}

// ---------------------------------------------------------------------------
// accum9: one block per (b, pixel-block). For all 9 neighbor targets q:
// e_q(p) = exp((dot(x_p, clst_q) - m_q)/tau), partial S[blk][q][c] = sum e*x,
// denp[blk][q] = sum e.
// ---------------------------------------------------------------------------
__global__ __launch_bounds__(256) void accum9_kernel(const float* __restrict__ xn,
                                                     const float* __restrict__ clst,
                                                     const float* __restrict__ pm,
                                                     float* __restrict__ S,
                                                     float* __restrict__ denp) {
    int blk = blockIdx.x;           // b*256 + block
    int b = blk >> 8;
    int cell = blk & 255;
    int bi = cell >> 4, bj = cell & 15;
    int t = threadIdx.x;

    __shared__ float sclst[9][32];
    __shared__ float sm[9];
    __shared__ float se[9][256];
    __shared__ float sacc[8][9][32];
    __shared__ float sdw[4][9];

    for (int u = t; u < 288; u += 256) {
        int q = u >> 5, c = u & 31;
        int ii = bi + q / 3 - 1, jj = bj + q % 3 - 1;
        float v = 0.f;
        if (ii >= 0 && ii < 16 && jj >= 0 && jj < 16)
            v = clst[((size_t)(b * 256 + ii * 16 + jj)) * 32 + c];
        sclst[q][c] = v;
    }
    if (t < 9) {
        int i = bi + t / 3 - 1, j = bj + t % 3 - 1;
        float m = INFINITY;          // invalid target: e forced to 0 anyway
        if (i >= 0 && i < 16 && j >= 0 && j < 16) {
            m = -INFINITY;
            for (int u = 0; u < 9; ++u) {
                int oy = u / 3 - 1, ox = u % 3 - 1;
                int ii = i + oy, jj = j + ox;
                if (ii >= 0 && ii < 16 && jj >= 0 && jj < 16)
                    m = fmaxf(m, pm[((b * 256 + ii * 16 + jj) * 9) + (1 - oy) * 3 + (1 - ox)]);
            }
        }
        sm[t] = m;
    }
    __syncthreads();

    int y = bi * 16 + (t >> 4), xx = bj * 16 + (t & 15);
    const float4* f4 = (const float4*)(xn + ((size_t)(b * 65536 + y * 256 + xx)) * 32);
    float fv[32];
#pragma unroll
    for (int q = 0; q < 8; ++q) {
        float4 v = f4[q];
        fv[4*q] = v.x; fv[4*q+1] = v.y; fv[4*q+2] = v.z; fv[4*q+3] = v.w;
    }

    float e[9];
    int wid = t >> 6, lane = t & 63;
#pragma unroll
    for (int q = 0; q < 9; ++q) {
        float s = 0.f;
#pragma unroll
        for (int c = 0; c < 32; ++c) s += fv[c] * sclst[q][c];
        float ev = (s == 0.f) ? 0.f : expf((s - sm[q]) * TAU_INV);
        e[q] = ev;
        se[q][t] = ev;
        // block sum of e for denominator partial
        float d = ev;
#pragma unroll
        for (int k = 32; k >= 1; k >>= 1) d += __shfl_xor(d, k);
        if (lane == 0) sdw[wid][q] = d;
    }
    __syncthreads();
    if (t < 9) denp[blk * 9 + t] = sdw[0][t] + sdw[1][t] + sdw[2][t] + sdw[3][t];

    // accumulation: thread = (c = t&31, pg = t>>5), 32 pixels each, 9 targets
    int c = t & 31, pg = t >> 5;
    const float* base = xn + ((size_t)(b * 65536 + bi * 16 * 256 + bj * 16)) * 32;
    float acc[9];
#pragma unroll
    for (int q = 0; q < 9; ++q) acc[q] = 0.f;
#pragma unroll
    for (int k = 0; k < 32; ++k) {
        int p = pg * 32 + k;
        float xv = base[(size_t)(p >> 4) * 8192 + (p & 15) * 32 + c];
#pragma unroll
        for (int q = 0; q < 9; ++q) acc[q] = fmaf(se[q][p], xv, acc[q]);
    }
#pragma unroll
    for (int q = 0; q < 9; ++q) sacc[pg][q][c] = acc[q];
    __syncthreads();

    // reduce 8 pg groups for 288 (q,c) outputs
    {
        int q = t >> 5, cc = t & 31;   // q 0..7
        float s8 = 0.f;
#pragma unroll
        for (int g = 0; g < 8; ++g) s8 += sacc[g][q][cc];
        S[((size_t)blk * 9 + q) * 32 + cc] = s8;
        if (t < 32) {
            float s9 = 0.f;
#pragma unroll
            for (int g = 0; g < 8; ++g) s9 += sacc[g][8][t];
            S[((size_t)blk * 9 + 8) * 32 + t] = s9;
        }
    }
}

// ---------------------------------------------------------------------------
// combine: per (b,cell,c): sum the 9 neighbor partials, L2-normalize.
// On the last iteration also write dcell, mcell and the transposed clst output.
// ---------------------------------------------------------------------------
__global__ __launch_bounds__(256) void combine_kernel(const float* __restrict__ S,
                                                      const float* __restrict__ denp,
                                                      const float* __restrict__ pm,
                                                      float* __restrict__ clst_out,
                                                      float* __restrict__ dcell,
                                                      float* __restrict__ mcell,
                                                      float* __restrict__ out_clst,
                                                      int last) {
    int t = threadIdx.x;
    int cellIdx = blockIdx.x * 8 + (t >> 5);  // 0..511
    int b = cellIdx >> 8;
    int cell = cellIdx & 255;
    int i = cell >> 4, j = cell & 15;
    int c = t & 31;
    float acc = 0.f;
#pragma unroll
    for (int u = 0; u < 9; ++u) {
        int oy = u / 3 - 1, ox = u % 3 - 1;
        int ii = i + oy, jj = j + ox;
        if (ii >= 0 && ii < 16 && jj >= 0 && jj < 16) {
            int src = ((b * 256 + ii * 16 + jj) * 9) + (1 - oy) * 3 + (1 - ox);
            acc += S[(size_t)src * 32 + c];
        }
    }
    float ss = acc * acc;
#pragma unroll
    for (int k = 16; k >= 1; k >>= 1) ss += __shfl_xor(ss, k);  // within 32-lane group
    float rn = 1.0f / sqrtf(ss);
    float val = acc * rn;
    clst_out[(size_t)cellIdx * 32 + c] = val;
    if (last) {
        out_clst[((size_t)b * 32 + c) * 256 + cell] = val;
        if (c == 0) {
            float dsum = 0.f;
            for (int u = 0; u < 9; ++u) {
                int oy = u / 3 - 1, ox = u % 3 - 1;
                int ii = i + oy, jj = j + ox;
                if (ii >= 0 && ii < 16 && jj >= 0 && jj < 16)
                    dsum += denp[((b * 256 + ii * 16 + jj) * 9) + (1 - oy) * 3 + (1 - ox)];
            }
            dcell[cellIdx] = dsum;
        }
        if (c == 1) {
            float m = -INFINITY;
            for (int u = 0; u < 9; ++u) {
                int oy = u / 3 - 1, ox = u % 3 - 1;
                int ii = i + oy, jj = j + ox;
                if (ii >= 0 && ii < 16 && jj >= 0 && jj < 16)
                    m = fmaxf(m, pm[((b * 256 + ii * 16 + jj) * 9) + (1 - oy) * 3 + (1 - ox)]);
            }
            mcell[cellIdx] = m;
        }
    }
}

// ---------------------------------------------------------------------------
// s2p_full: one block per (b, window-pos p). thread = cell. Writes EVERY
// element of s2p (valid weight or exact 0) -> no memset needed.
// s2p layout (b, 2304, 16, 16). clst here is the iteration-5 INPUT clst.
// ---------------------------------------------------------------------------
__global__ __launch_bounds__(256) void s2p_full_kernel(const float* __restrict__ xn,
                                                       const float* __restrict__ clst,
                                                       const float* __restrict__ mcell,
                                                       const float* __restrict__ dcell,
                                                       float* __restrict__ s2p) {
    int gid = blockIdx.x;            // b*2304 + p
    int b = gid / 2304;
    int p = gid % 2304;
    int ky = p / 48, kx = p % 48;
    int t = threadIdx.x;             // cell

    __shared__ float sclst[256 * 33];
    __shared__ float smv[256];
    __shared__ float srd[256];

    for (int u = t; u < 8192; u += 256)
        sclst[(u >> 5) * 33 + (u & 31)] = clst[(size_t)b * 8192 + u];
    smv[t] = mcell[b * 256 + t];
    srd[t] = 1.0f / dcell[b * 256 + t];
    __syncthreads();

    int i = t >> 4, j = t & 15;
    int y = i * 16 - 16 + ky;
    int xx = j * 16 - 16 + kx;
    float val = 0.f;
    if (y >= 0 && y < 256 && xx >= 0 && xx < 256) {
        const float* f = xn + ((size_t)(b * 65536 + y * 256 + xx)) * 32;
        const float* cl = sclst + t * 33;
        float s = 0.f;
#pragma unroll
        for (int c = 0; c < 32; ++c) s += f[c] * cl[c];
        if (s != 0.f) val = expf((s - smv[t]) * TAU_INV) * srd[t];
    }
    s2p[(size_t)gid * 256 + t] = val;
}

// ---------------------------------------------------------------------------
// p2s: per pixel, dot vs 3x3 candidate clusters, softmax over 9. (b, 9, H, W)
// ---------------------------------------------------------------------------
__global__ __launch_bounds__(256) void p2s_kernel(const float* __restrict__ xn,
                                                  const float* __restrict__ clst,
                                                  float* __restrict__ p2s) {
    int idx = blockIdx.x * 256 + threadIdx.x;  // B*H*W
    int b = idx >> 16;
    int rem = idx & 65535;
    int y = rem >> 8, xx = rem & 255;
    int i = y >> 4, j = xx >> 4;

    const float* f = xn + (size_t)idx * 32;
    float feat[32];
#pragma unroll
    for (int c = 0; c < 32; ++c) feat[c] = f[c];

    float l[9];
    float mx = -INFINITY;
#pragma unroll
    for (int q = 0; q < 9; ++q) {
        int qy = q / 3, qx = q % 3;
        int ci = i - 1 + qy, cj = j - 1 + qx;
        float s = 0.f;
        if (ci >= 0 && ci < 16 && cj >= 0 && cj < 16) {
            const float* cf = clst + ((size_t)b * 256 + ci * 16 + cj) * 32;
#pragma unroll
            for (int c = 0; c < 32; ++c) s += feat[c] * cf[c];
        }
        l[q] = (s == 0.f) ? -INFINITY : s * TAU_INV;
        mx = fmaxf(mx, l[q]);
    }
    float e[9];
    float sum = 0.f;
#pragma unroll
    for (int q = 0; q < 9; ++q) {
        e[q] = (l[q] == -INFINITY) ? 0.f : expf(l[q] - mx);
        sum += e[q];
    }
    float rs = 1.0f / sum;
#pragma unroll
    for (int q = 0; q < 9; ++q) {
        p2s[((size_t)b * 9 + q) * 65536 + rem] = e[q] * rs;
    }
}

extern "C" void kernel_launch(void* const* d_in, const int* in_sizes, int n_in,
                              void* d_out, int out_size, void* d_ws, size_t ws_size,
                              hipStream_t stream) {
    const float* x = (const float*)d_in[0];
    float* out = (float*)d_out;

    float* out_clst = out;                       // 2*32*16*16      = 16384
    float* out_p2s  = out + 16384;               // 2*9*256*256     = 1179648
    float* out_s2p  = out + 16384 + 1179648;     // 2*2304*16*16    = 1179648

    float* ws = (float*)d_ws;
    float* xn    = ws;                           // 4,194,304 floats
    float* clstA = xn + 4194304;                 // 16,384
    float* clstB = clstA + 16384;                // 16,384
    float* pm    = clstB + 16384;                // 4,608
    float* S     = pm + 4608;                    // 147,456
    float* denp  = S + 147456;                   // 4,608
    float* dcell = denp + 4608;                  // 512
    float* mcell = dcell + 512;                  // 512

    prep_init_kernel<<<512, 256, 0, stream>>>(x, xn, clstA);

    float* cin = clstA;
    float* cout = clstB;
    for (int it = 0; it < 5; ++it) {
        pm_kernel<<<512, 256, 0, stream>>>(xn, cin, pm);
        accum9_kernel<<<512, 256, 0, stream>>>(xn, cin, pm, S, denp);
        combine_kernel<<<64, 256, 0, stream>>>(S, denp, pm, cout, dcell, mcell,
                                               out_clst, (it == 4) ? 1 : 0);
        float* tmp = cin; cin = cout; cout = tmp;
    }
    // cin = final clst; cout = clst input of iteration 5
    s2p_full_kernel<<<4608, 256, 0, stream>>>(xn, cout, mcell, dcell, out_s2p);
    p2s_kernel<<<512, 256, 0, stream>>>(xn, cin, out_p2s);
}

// Round 5
// 124.690 us; speedup vs baseline: 5.0976x; 1.3680x over previous
//
#include <hip/hip_runtime.h>
#include <math.h>

// Problem constants (b=2, c=32, H=W=256, 256 superpixels, R=1, 5 iters, tau=0.01)
#define TAU_INV 100.0f
// Fixed softmax shift: dots of unit vectors lie in [-1,1]; every cell window's
// max dot is > 0 (the weighted average of dots equals ||weighted mean|| > 0),
// so with shift 0.5 the exponents are in [-150, 50]: e <= 5.2e21 (no overflow),
// den >= e^-50 > 0 (no all-zero window). Softmax is shift-invariant, so the
// ratios match the reference's true-max softmax. IMPORTANT: downstream code
// must divide by den BEFORE squaring anything (see combine_kernel) -- the
// unnormalized accumulator can reach ~1e24 and its square overflows f32.
#define SHIFTED_EXP(s) expf(((s) - 0.5f) * TAU_INV)

// ---------------------------------------------------------------------------
// prep_init: one block per (b, 16x16 pixel block).
//  - per-pixel L2-normalize x along channels -> xn[b][y][x][c] (channel-last)
//  - raw block mean over the 16x16 block, L2-normalized -> clst[b][cell][c]
// ---------------------------------------------------------------------------
__global__ __launch_bounds__(256) void prep_init_kernel(const float* __restrict__ x,
                                                        float* __restrict__ xn,
                                                        float* __restrict__ clst) {
    int blk = blockIdx.x;          // b*256 + cell
    int b = blk >> 8;
    int cell = blk & 255;
    int ci = cell >> 4, cj = cell & 15;
    int t = threadIdx.x;
    int py = t >> 4, px = t & 15;
    int y = ci * 16 + py, xx = cj * 16 + px;
    int rem = y * 256 + xx;

    __shared__ float sraw[256 * 33];   // padded stride 33
    __shared__ float red[256];

    const float* xb = x + (size_t)b * (32 * 65536);
    float v[32];
    float ss = 0.f;
#pragma unroll
    for (int c = 0; c < 32; ++c) {
        float tv = xb[c * 65536 + rem];
        v[c] = tv;
        ss += tv * tv;
        sraw[t * 33 + c] = tv;
    }
    float rn = 1.0f / sqrtf(ss);
    float4* outp = (float4*)(xn + ((size_t)b * 65536 + rem) * 32);
#pragma unroll
    for (int q = 0; q < 8; ++q)
        outp[q] = make_float4(v[4*q]*rn, v[4*q+1]*rn, v[4*q+2]*rn, v[4*q+3]*rn);

    __syncthreads();
    // per-channel sum over 256 pixels: thread = (c = t&31, pg = t>>5)
    int c = t & 31, pg = t >> 5;
    float acc = 0.f;
#pragma unroll
    for (int k = 0; k < 32; ++k) acc += sraw[(pg * 32 + k) * 33 + c];
    red[t] = acc;
    __syncthreads();
    if (t < 128) red[t] += red[t + 128];
    __syncthreads();
    if (t < 64) red[t] += red[t + 64];
    __syncthreads();
    if (t < 32) {
        float m = (red[t] + red[t + 32]) * (1.0f / 256.0f);
        float p = m * m;
#pragma unroll
        for (int k = 16; k >= 1; k >>= 1) p += __shfl_xor(p, k);
        clst[(size_t)blk * 32 + t] = m * (1.0f / sqrtf(p));
    }
}

// ---------------------------------------------------------------------------
// accum9: one block per (b, pixel-block). For all 9 neighbor targets q:
// e_q(p) = exp((dot(x_p, clst_q) - 0.5)/tau), partial S[blk][q][c] = sum e*x,
// denp[blk][q] = sum e.  (No per-cell max needed: fixed shift, see above.)
// ---------------------------------------------------------------------------
__global__ __launch_bounds__(256) void accum9_kernel(const float* __restrict__ xn,
                                                     const float* __restrict__ clst,
                                                     float* __restrict__ S,
                                                     float* __restrict__ denp) {
    int blk = blockIdx.x;           // b*256 + block
    int b = blk >> 8;
    int cell = blk & 255;
    int bi = cell >> 4, bj = cell & 15;
    int t = threadIdx.x;

    __shared__ float sclst[9][32];
    __shared__ float se[9][256];
    __shared__ float sacc[8][9][32];
    __shared__ float sdw[4][9];

    for (int u = t; u < 288; u += 256) {
        int q = u >> 5, c = u & 31;
        int ii = bi + q / 3 - 1, jj = bj + q % 3 - 1;
        float v = 0.f;
        if (ii >= 0 && ii < 16 && jj >= 0 && jj < 16)
            v = clst[((size_t)(b * 256 + ii * 16 + jj)) * 32 + c];
        sclst[q][c] = v;
    }
    __syncthreads();

    int y = bi * 16 + (t >> 4), xx = bj * 16 + (t & 15);
    const float4* f4 = (const float4*)(xn + ((size_t)(b * 65536 + y * 256 + xx)) * 32);
    float fv[32];
#pragma unroll
    for (int q = 0; q < 8; ++q) {
        float4 v = f4[q];
        fv[4*q] = v.x; fv[4*q+1] = v.y; fv[4*q+2] = v.z; fv[4*q+3] = v.w;
    }

    int wid = t >> 6, lane = t & 63;
#pragma unroll
    for (int q = 0; q < 9; ++q) {
        float s = 0.f;
#pragma unroll
        for (int c = 0; c < 32; ++c) s += fv[c] * sclst[q][c];
        // s==0 <=> OOB target (sclst=0) or exact-zero dot; reference masks both.
        float ev = (s == 0.f) ? 0.f : SHIFTED_EXP(s);
        se[q][t] = ev;
        float d = ev;
#pragma unroll
        for (int k = 32; k >= 1; k >>= 1) d += __shfl_xor(d, k);
        if (lane == 0) sdw[wid][q] = d;
    }
    __syncthreads();
    if (t < 9) denp[blk * 9 + t] = sdw[0][t] + sdw[1][t] + sdw[2][t] + sdw[3][t];

    // accumulation: thread = (c = t&31, pg = t>>5), 32 pixels each, 9 targets
    int c = t & 31, pg = t >> 5;
    const float* base = xn + ((size_t)(b * 65536 + bi * 16 * 256 + bj * 16)) * 32;
    float acc[9];
#pragma unroll
    for (int q = 0; q < 9; ++q) acc[q] = 0.f;
#pragma unroll
    for (int k = 0; k < 32; ++k) {
        int p = pg * 32 + k;
        float xv = base[(size_t)(p >> 4) * 8192 + (p & 15) * 32 + c];
#pragma unroll
        for (int q = 0; q < 9; ++q) acc[q] = fmaf(se[q][p], xv, acc[q]);
    }
#pragma unroll
    for (int q = 0; q < 9; ++q) sacc[pg][q][c] = acc[q];
    __syncthreads();

    // reduce 8 pg groups for 288 (q,c) outputs
    {
        int q = t >> 5, cc = t & 31;   // q 0..7
        float s8 = 0.f;
#pragma unroll
        for (int g = 0; g < 8; ++g) s8 += sacc[g][q][cc];
        S[((size_t)blk * 9 + q) * 32 + cc] = s8;
        if (t < 32) {
            float s9 = 0.f;
#pragma unroll
            for (int g = 0; g < 8; ++g) s9 += sacc[g][8][t];
            S[((size_t)blk * 9 + 8) * 32 + t] = s9;
        }
    }
}

// ---------------------------------------------------------------------------
// combine: per (b,cell,c): sum the 9 neighbor partials, divide by the summed
// softmax denominator (convex combination, ||mean|| <= 1 -- avoids f32
// overflow when squaring), then L2-normalize. Writes dcell every iteration;
// on the last also writes the transposed clst output.
// ---------------------------------------------------------------------------
__global__ __launch_bounds__(256) void combine_kernel(const float* __restrict__ S,
                                                      const float* __restrict__ denp,
                                                      float* __restrict__ clst_out,
                                                      float* __restrict__ dcell,
                                                      float* __restrict__ out_clst,
                                                      int last) {
    int t = threadIdx.x;
    int cellIdx = blockIdx.x * 8 + (t >> 5);  // 0..511
    int b = cellIdx >> 8;
    int cell = cellIdx & 255;
    int i = cell >> 4, j = cell & 15;
    int c = t & 31;
    float acc = 0.f;
    float den = 0.f;
#pragma unroll
    for (int u = 0; u < 9; ++u) {
        int oy = u / 3 - 1, ox = u % 3 - 1;
        int ii = i + oy, jj = j + ox;
        if (ii >= 0 && ii < 16 && jj >= 0 && jj < 16) {
            int src = ((b * 256 + ii * 16 + jj) * 9) + (1 - oy) * 3 + (1 - ox);
            acc += S[(size_t)src * 32 + c];
            den += denp[src];
        }
    }
    float mean = acc / den;                 // safe: den >= e^-50 > 0
    float ss = mean * mean;
#pragma unroll
    for (int k = 16; k >= 1; k >>= 1) ss += __shfl_xor(ss, k);  // within 32-lane group
    float rn = 1.0f / sqrtf(ss);
    float val = mean * rn;
    clst_out[(size_t)cellIdx * 32 + c] = val;
    if (c == 0) dcell[cellIdx] = den;
    if (last) out_clst[((size_t)b * 32 + c) * 256 + cell] = val;
}

// ---------------------------------------------------------------------------
// s2p_full: one block per (b, chunk of 9 window positions). thread = cell.
// Writes EVERY element of s2p (valid weight or exact 0) -> no memset needed.
// Cluster table (32 KB) loaded to LDS once, reused for 9 positions.
// s2p layout (b, 2304, 16, 16). clst here is the iteration-5 INPUT clst.
// ---------------------------------------------------------------------------
__global__ __launch_bounds__(256) void s2p_full_kernel(const float* __restrict__ xn,
                                                       const float* __restrict__ clst,
                                                       const float* __restrict__ dcell,
                                                       float* __restrict__ s2p) {
    int blk = blockIdx.x;            // 512: b*256 + chunk
    int b = blk >> 8;
    int chunk = blk & 255;
    int t = threadIdx.x;             // cell

    __shared__ float sclst[256 * 33];
    __shared__ float srd[256];

    for (int u = t; u < 8192; u += 256)
        sclst[(u >> 5) * 33 + (u & 31)] = clst[(size_t)b * 8192 + u];
    srd[t] = 1.0f / dcell[b * 256 + t];
    __syncthreads();

    int i = t >> 4, j = t & 15;
    const float* cl = sclst + t * 33;
    float rd = srd[t];
#pragma unroll
    for (int u = 0; u < 9; ++u) {
        int p = chunk * 9 + u;       // 0..2303
        int ky = p / 48, kx = p % 48;
        int y = i * 16 - 16 + ky;
        int xx = j * 16 - 16 + kx;
        float val = 0.f;
        if (y >= 0 && y < 256 && xx >= 0 && xx < 256) {
            const float* f = xn + ((size_t)(b * 65536 + y * 256 + xx)) * 32;
            float s = 0.f;
#pragma unroll
            for (int c = 0; c < 32; ++c) s += f[c] * cl[c];
            if (s != 0.f) val = SHIFTED_EXP(s) * rd;
        }
        s2p[(size_t)(b * 2304 + p) * 256 + t] = val;
    }
}

// ---------------------------------------------------------------------------
// p2s: per pixel, dot vs 3x3 candidate clusters, softmax over 9. (b, 9, H, W)
// ---------------------------------------------------------------------------
__global__ __launch_bounds__(256) void p2s_kernel(const float* __restrict__ xn,
                                                  const float* __restrict__ clst,
                                                  float* __restrict__ p2s) {
    int idx = blockIdx.x * 256 + threadIdx.x;  // B*H*W
    int b = idx >> 16;
    int rem = idx & 65535;
    int y = rem >> 8, xx = rem & 255;
    int i = y >> 4, j = xx >> 4;

    const float* f = xn + (size_t)idx * 32;
    float feat[32];
#pragma unroll
    for (int c = 0; c < 32; ++c) feat[c] = f[c];

    float l[9];
    float mx = -INFINITY;
#pragma unroll
    for (int q = 0; q < 9; ++q) {
        int qy = q / 3, qx = q % 3;
        int ci = i - 1 + qy, cj = j - 1 + qx;
        float s = 0.f;
        if (ci >= 0 && ci < 16 && cj >= 0 && cj < 16) {
            const float* cf = clst + ((size_t)b * 256 + ci * 16 + cj) * 32;
#pragma unroll
            for (int c = 0; c < 32; ++c) s += feat[c] * cf[c];
        }
        l[q] = (s == 0.f) ? -INFINITY : s * TAU_INV;
        mx = fmaxf(mx, l[q]);
    }
    float e[9];
    float sum = 0.f;
#pragma unroll
    for (int q = 0; q < 9; ++q) {
        e[q] = (l[q] == -INFINITY) ? 0.f : expf(l[q] - mx);
        sum += e[q];
    }
    float rs = 1.0f / sum;
#pragma unroll
    for (int q = 0; q < 9; ++q) {
        p2s[((size_t)b * 9 + q) * 65536 + rem] = e[q] * rs;
    }
}

extern "C" void kernel_launch(void* const* d_in, const int* in_sizes, int n_in,
                              void* d_out, int out_size, void* d_ws, size_t ws_size,
                              hipStream_t stream) {
    const float* x = (const float*)d_in[0];
    float* out = (float*)d_out;

    float* out_clst = out;                       // 2*32*16*16      = 16384
    float* out_p2s  = out + 16384;               // 2*9*256*256     = 1179648
    float* out_s2p  = out + 16384 + 1179648;     // 2*2304*16*16    = 1179648

    float* ws = (float*)d_ws;
    float* xn    = ws;                           // 4,194,304 floats
    float* clstA = xn + 4194304;                 // 16,384
    float* clstB = clstA + 16384;                // 16,384
    float* S     = clstB + 16384;                // 147,456
    float* denp  = S + 147456;                   // 4,608
    float* dcell = denp + 4608;                  // 512

    prep_init_kernel<<<512, 256, 0, stream>>>(x, xn, clstA);

    float* cin = clstA;
    float* cout = clstB;
    for (int it = 0; it < 5; ++it) {
        accum9_kernel<<<512, 256, 0, stream>>>(xn, cin, S, denp);
        combine_kernel<<<64, 256, 0, stream>>>(S, denp, cout, dcell,
                                               out_clst, (it == 4) ? 1 : 0);
        float* tmp = cin; cin = cout; cout = tmp;
    }
    // cin = final clst; cout = clst input of iteration 5
    s2p_full_kernel<<<512, 256, 0, stream>>>(xn, cout, dcell, out_s2p);
    p2s_kernel<<<512, 256, 0, stream>>>(xn, cin, out_p2s);
}

// Round 7
// 113.952 us; speedup vs baseline: 5.5779x; 1.0942x over previous
//
#include <hip/hip_runtime.h>
#include <math.h>

// Problem constants (b=2, c=32, H=W=256, 256 superpixels, R=1, 5 iters, tau=0.01)
#define TAU_INV 100.0f
// Fixed softmax shift: dots of unit vectors lie in [-1,1]; every cell window's
// max dot is > 0, so with shift 0.5 exponents are in [-150, 50]: e <= 5.2e21
// (no overflow), den > 0 (no all-zero window). Softmax is shift-invariant, so
// ratios match the reference's true-max softmax. Downstream divides by den
// BEFORE squaring (convex combination, ||mean|| <= 1) to avoid f32 overflow.
#define SHIFTED_EXP(s) expf(((s) - 0.5f) * TAU_INV)

// ---------------------------------------------------------------------------
// combine_one: cluster update for target cell (ti,tj) from iteration partials.
// Executed by an aligned 32-lane group; c = lane's channel. Deterministic
// (fixed summation order) so redundant recomputation in different blocks is
// bitwise identical. Returns 0 for out-of-grid targets (matches zero-padding).
// ---------------------------------------------------------------------------
__device__ inline float combine_one(const float* __restrict__ Sin,
                                    const float* __restrict__ dpin,
                                    int b, int ti, int tj, int c) {
    float acc = 0.f, den = 0.f;
    if (ti >= 0 && ti < 16 && tj >= 0 && tj < 16) {
#pragma unroll
        for (int u = 0; u < 9; ++u) {
            int oy = u / 3 - 1, ox = u % 3 - 1;
            int ii = ti + oy, jj = tj + ox;
            if (ii >= 0 && ii < 16 && jj >= 0 && jj < 16) {
                int src = ((b * 256 + ii * 16 + jj) * 9) + (1 - oy) * 3 + (1 - ox);
                acc += Sin[(size_t)src * 32 + c];
                den += dpin[src];
            }
        }
    }
    float mean = (den > 0.f) ? acc / den : 0.f;   // ||mean|| <= 1
    float p = mean * mean;
#pragma unroll
    for (int k = 16; k >= 1; k >>= 1) p += __shfl_xor(p, k);
    return (p > 0.f) ? mean * (1.0f / sqrtf(p)) : 0.f;
}

// ---------------------------------------------------------------------------
// prep_init: one block per (b, 16x16 pixel block).
//  - per-pixel L2-normalize x along channels -> xn[b][y][x][c] (channel-last)
//  - raw block mean over the 16x16 block, L2-normalized -> clst0[b][cell][c]
// ---------------------------------------------------------------------------
__global__ __launch_bounds__(256) void prep_init_kernel(const float* __restrict__ x,
                                                        float* __restrict__ xn,
                                                        float* __restrict__ clst0) {
    int blk = blockIdx.x;          // b*256 + cell
    int b = blk >> 8;
    int cell = blk & 255;
    int ci = cell >> 4, cj = cell & 15;
    int t = threadIdx.x;
    int py = t >> 4, px = t & 15;
    int y = ci * 16 + py, xx = cj * 16 + px;
    int rem = y * 256 + xx;

    __shared__ float sraw[256 * 33];   // padded stride 33
    __shared__ float red[256];

    const float* xb = x + (size_t)b * (32 * 65536);
    float v[32];
    float ss = 0.f;
#pragma unroll
    for (int c = 0; c < 32; ++c) {
        float tv = xb[c * 65536 + rem];
        v[c] = tv;
        ss += tv * tv;
        sraw[t * 33 + c] = tv;
    }
    float rn = 1.0f / sqrtf(ss);
    float4* outp = (float4*)(xn + ((size_t)b * 65536 + rem) * 32);
#pragma unroll
    for (int q = 0; q < 8; ++q)
        outp[q] = make_float4(v[4*q]*rn, v[4*q+1]*rn, v[4*q+2]*rn, v[4*q+3]*rn);

    __syncthreads();
    int c = t & 31, pg = t >> 5;
    float acc = 0.f;
#pragma unroll
    for (int k = 0; k < 32; ++k) acc += sraw[(pg * 32 + k) * 33 + c];
    red[t] = acc;
    __syncthreads();
    if (t < 128) red[t] += red[t + 128];
    __syncthreads();
    if (t < 64) red[t] += red[t + 64];
    __syncthreads();
    if (t < 32) {
        float m = (red[t] + red[t + 32]) * (1.0f / 256.0f);
        float p = m * m;
#pragma unroll
        for (int k = 16; k >= 1; k >>= 1) p += __shfl_xor(p, k);
        clst0[(size_t)blk * 32 + t] = m * (1.0f / sqrtf(p));
    }
}

// ---------------------------------------------------------------------------
// accum9c: one block per (b, pixel-block). Head: build the 9 neighbor clusters
// either from clst0 (it==0) or by redundant deterministic combine of the
// previous iteration's partials (it>=1) -- this replaces the combine kernel.
// Body: e_q(p)=exp((dot-0.5)/tau); partials Sout[blk][q][c]=sum e*x,
// dpout[blk][q]=sum e. At it==4 also stores own-cell cluster (iter-5 input).
// ---------------------------------------------------------------------------
__global__ __launch_bounds__(256) void accum9c_kernel(const float* __restrict__ xn,
                                                      const float* __restrict__ clst0,
                                                      const float* __restrict__ Sin,
                                                      const float* __restrict__ dpin,
                                                      float* __restrict__ Sout,
                                                      float* __restrict__ dpout,
                                                      float* __restrict__ clstin5,
                                                      int it) {
    int blk = blockIdx.x;           // b*256 + block
    int b = blk >> 8;
    int cell = blk & 255;
    int bi = cell >> 4, bj = cell & 15;
    int t = threadIdx.x;

    __shared__ float sclst[9][32];
    __shared__ float se[9][256];
    __shared__ float sacc[8][9][32];
    __shared__ float sdw[4][9];

    if (it == 0) {
        for (int u = t; u < 288; u += 256) {
            int q = u >> 5, c = u & 31;
            int ii = bi + q / 3 - 1, jj = bj + q % 3 - 1;
            float v = 0.f;
            if (ii >= 0 && ii < 16 && jj >= 0 && jj < 16)
                v = clst0[((size_t)(b * 256 + ii * 16 + jj)) * 32 + c];
            sclst[q][c] = v;
        }
    } else {
        {
            int q = t >> 5, c = t & 31;              // q = 0..7
            float v = combine_one(Sin, dpin, b, bi + q / 3 - 1, bj + q % 3 - 1, c);
            sclst[q][c] = v;
            if (it == 4 && q == 4)                   // own cell = iter-5 input clst
                clstin5[(size_t)blk * 32 + c] = v;
        }
        if (t < 32)                                  // q = 8 -> offset (1,1)
            sclst[8][t] = combine_one(Sin, dpin, b, bi + 1, bj + 1, t);
    }
    __syncthreads();

    int y = bi * 16 + (t >> 4), xx = bj * 16 + (t & 15);
    const float4* f4 = (const float4*)(xn + ((size_t)(b * 65536 + y * 256 + xx)) * 32);
    float fv[32];
#pragma unroll
    for (int q = 0; q < 8; ++q) {
        float4 v = f4[q];
        fv[4*q] = v.x; fv[4*q+1] = v.y; fv[4*q+2] = v.z; fv[4*q+3] = v.w;
    }

    int wid = t >> 6, lane = t & 63;
#pragma unroll
    for (int q = 0; q < 9; ++q) {
        float s = 0.f;
#pragma unroll
        for (int c = 0; c < 32; ++c) s += fv[c] * sclst[q][c];
        // s==0 <=> OOB target (sclst=0) or exact-zero dot; reference masks both.
        float ev = (s == 0.f) ? 0.f : SHIFTED_EXP(s);
        se[q][t] = ev;
        float d = ev;
#pragma unroll
        for (int k = 32; k >= 1; k >>= 1) d += __shfl_xor(d, k);
        if (lane == 0) sdw[wid][q] = d;
    }
    __syncthreads();
    if (t < 9) dpout[blk * 9 + t] = sdw[0][t] + sdw[1][t] + sdw[2][t] + sdw[3][t];

    // accumulation: thread = (c = t&31, pg = t>>5), 32 pixels each, 9 targets
    {
        int c = t & 31, pg = t >> 5;
        const float* base = xn + ((size_t)(b * 65536 + bi * 16 * 256 + bj * 16)) * 32;
        float acc[9];
#pragma unroll
        for (int q = 0; q < 9; ++q) acc[q] = 0.f;
#pragma unroll
        for (int k = 0; k < 32; ++k) {
            int p = pg * 32 + k;
            float xv = base[(size_t)(p >> 4) * 8192 + (p & 15) * 32 + c];
#pragma unroll
            for (int q = 0; q < 9; ++q) acc[q] = fmaf(se[q][p], xv, acc[q]);
        }
#pragma unroll
        for (int q = 0; q < 9; ++q) sacc[pg][q][c] = acc[q];
    }
    __syncthreads();

    {
        int q = t >> 5, cc = t & 31;   // q 0..7
        float s8 = 0.f;
#pragma unroll
        for (int g = 0; g < 8; ++g) s8 += sacc[g][q][cc];
        Sout[((size_t)blk * 9 + q) * 32 + cc] = s8;
        if (t < 32) {
            float s9 = 0.f;
#pragma unroll
            for (int g = 0; g < 8; ++g) s9 += sacc[g][8][t];
            Sout[((size_t)blk * 9 + 8) * 32 + t] = s9;
        }
    }
}

// ---------------------------------------------------------------------------
// tail: one block per (b, cell). Final combine (own + 8 neighbors, redundant
// deterministic) -> clst output + p2s candidates; dcell from dp5; s2p (the 9
// window positions owned by this cell-chunk, covering the whole s2p output);
// p2s for this block's own 256 pixels.
// ---------------------------------------------------------------------------
__global__ __launch_bounds__(256) void tail_kernel(const float* __restrict__ xn,
                                                   const float* __restrict__ Sin,
                                                   const float* __restrict__ dpin,
                                                   const float* __restrict__ clstin5,
                                                   float* __restrict__ out_clst,
                                                   float* __restrict__ out_p2s,
                                                   float* __restrict__ out_s2p) {
    int blk = blockIdx.x;
    int b = blk >> 8;
    int cell = blk & 255;
    int ci = cell >> 4, cj = cell & 15;
    int t = threadIdx.x;

    __shared__ float sx[256 * 33];   // clstin5 table (for s2p)
    __shared__ float sclst[9][32];   // final clst of 3x3 hood (for p2s)
    __shared__ float srd[256];       // 1/den per target cell (for s2p)

    {
        int q = t >> 5, c = t & 31;              // q = 0..7
        float v = combine_one(Sin, dpin, b, ci + q / 3 - 1, cj + q % 3 - 1, c);
        sclst[q][c] = v;
        if (q == 4)                              // own cell: final clst output
            out_clst[((size_t)b * 32 + c) * 256 + cell] = v;
    }
    if (t < 32)
        sclst[8][t] = combine_one(Sin, dpin, b, ci + 1, cj + 1, t);

    for (int u = t; u < 8192; u += 256)
        sx[(u >> 5) * 33 + (u & 31)] = clstin5[(size_t)b * 8192 + u];

    {   // den of iteration 5 per target cell t
        int i = t >> 4, j = t & 15;
        float den = 0.f;
#pragma unroll
        for (int u = 0; u < 9; ++u) {
            int oy = u / 3 - 1, ox = u % 3 - 1;
            int ii = i + oy, jj = j + ox;
            if (ii >= 0 && ii < 16 && jj >= 0 && jj < 16)
                den += dpin[((b * 256 + ii * 16 + jj) * 9) + (1 - oy) * 3 + (1 - ox)];
        }
        srd[t] = 1.0f / den;                     // den > 0 always (valid cell)
    }
    __syncthreads();

    // s2p: window positions p = cell*9+u; thread = target cell t.
    {
        int i = t >> 4, j = t & 15;
        const float* cl = sx + t * 33;
        float rd = srd[t];
#pragma unroll
        for (int u = 0; u < 9; ++u) {
            int p = cell * 9 + u;                // 0..2303
            int ky = p / 48, kx = p % 48;
            int yy = i * 16 - 16 + ky;
            int xq = j * 16 - 16 + kx;
            float val = 0.f;
            if (yy >= 0 && yy < 256 && xq >= 0 && xq < 256) {
                const float* f = xn + ((size_t)(b * 65536 + yy * 256 + xq)) * 32;
                float s = 0.f;
#pragma unroll
                for (int c = 0; c < 32; ++c) s += f[c] * cl[c];
                if (s != 0.f) val = SHIFTED_EXP(s) * rd;
            }
            out_s2p[(size_t)(b * 2304 + p) * 256 + t] = val;
        }
    }

    // p2s for own pixel
    {
        int py = t >> 4, px = t & 15;
        int rem = (ci * 16 + py) * 256 + cj * 16 + px;
        const float4* f4 = (const float4*)(xn + ((size_t)b * 65536 + rem) * 32);
        float fv[32];
#pragma unroll
        for (int q = 0; q < 8; ++q) {
            float4 v = f4[q];
            fv[4*q] = v.x; fv[4*q+1] = v.y; fv[4*q+2] = v.z; fv[4*q+3] = v.w;
        }
        float l[9];
        float mx = -INFINITY;
#pragma unroll
        for (int q = 0; q < 9; ++q) {
            float s = 0.f;
#pragma unroll
            for (int c = 0; c < 32; ++c) s += fv[c] * sclst[q][c];
            l[q] = (s == 0.f) ? -INFINITY : s * TAU_INV;
            mx = fmaxf(mx, l[q]);
        }
        float e[9], sum = 0.f;
#pragma unroll
        for (int q = 0; q < 9; ++q) {
            e[q] = (l[q] == -INFINITY) ? 0.f : expf(l[q] - mx);
            sum += e[q];
        }
        float rs = 1.0f / sum;
#pragma unroll
        for (int q = 0; q < 9; ++q)
            out_p2s[((size_t)b * 9 + q) * 65536 + rem] = e[q] * rs;
    }
}

extern "C" void kernel_launch(void* const* d_in, const int* in_sizes, int n_in,
                              void* d_out, int out_size, void* d_ws, size_t ws_size,
                              hipStream_t stream) {
    const float* x = (const float*)d_in[0];
    float* out = (float*)d_out;

    float* out_clst = out;                       // 2*32*16*16      = 16384
    float* out_p2s  = out + 16384;               // 2*9*256*256     = 1179648
    float* out_s2p  = out + 16384 + 1179648;     // 2*2304*16*16    = 1179648

    float* ws = (float*)d_ws;
    float* xn      = ws;                         // 4,194,304
    float* clst0   = xn + 4194304;               // 16,384
    float* Sa      = clst0 + 16384;              // 147,456
    float* Sb      = Sa + 147456;                // 147,456
    float* dpa     = Sb + 147456;                // 4,608
    float* dpb     = dpa + 4608;                 // 4,608
    float* clstin5 = dpb + 4608;                 // 16,384
    // total ~18.1 MB << ws_size

    prep_init_kernel<<<512, 256, 0, stream>>>(x, xn, clst0);

    // it0 reads clst0 (Sin/dpin unread), writes B; then alternate.
    float* Sin = Sa;  float* dpin = dpa;
    float* Sout = Sb; float* dpout = dpb;
    for (int it = 0; it < 5; ++it) {
        accum9c_kernel<<<512, 256, 0, stream>>>(xn, clst0, Sin, dpin,
                                                Sout, dpout, clstin5, it);
        float* ts = Sin; Sin = Sout; Sout = ts;
        float* td = dpin; dpin = dpout; dpout = td;
    }
    // Sin/dpin now hold S5/dp5
    tail_kernel<<<512, 256, 0, stream>>>(xn, Sin, dpin, clstin5,
                                         out_clst, out_p2s, out_s2p);
}

// Round 8
// 101.829 us; speedup vs baseline: 6.2420x; 1.1191x over previous
//
#include <hip/hip_runtime.h>
#include <math.h>

// Problem constants (b=2, c=32, H=W=256, 256 superpixels, R=1, 5 iters, tau=0.01)
#define TAU_INV 100.0f
// Fixed softmax shift: dots of unit vectors lie in [-1,1]; every cell window's
// max dot is > 0, so with shift 0.5 exponents are in [-150, 50]: e <= 5.2e21
// (no overflow), den > 0 (no all-zero window). Softmax is shift-invariant, so
// ratios match the reference's true-max softmax. Downstream divides by den
// BEFORE squaring (convex combination, ||mean|| <= 1) to avoid f32 overflow.
#define SHIFTED_EXP(s) expf(((s) - 0.5f) * TAU_INV)

// ---------------------------------------------------------------------------
// combine_one: cluster update for target cell (ti,tj) from iteration partials.
// Executed by an aligned 32-lane group; c = lane's channel. Deterministic
// (fixed summation order) so redundant recomputation in different blocks is
// bitwise identical. Returns 0 for out-of-grid targets (matches zero-padding).
// ---------------------------------------------------------------------------
__device__ inline float combine_one(const float* __restrict__ Sin,
                                    const float* __restrict__ dpin,
                                    int b, int ti, int tj, int c) {
    float acc = 0.f, den = 0.f;
    if (ti >= 0 && ti < 16 && tj >= 0 && tj < 16) {
#pragma unroll
        for (int u = 0; u < 9; ++u) {
            int oy = u / 3 - 1, ox = u % 3 - 1;
            int ii = ti + oy, jj = tj + ox;
            if (ii >= 0 && ii < 16 && jj >= 0 && jj < 16) {
                int src = ((b * 256 + ii * 16 + jj) * 9) + (1 - oy) * 3 + (1 - ox);
                acc += Sin[(size_t)src * 32 + c];
                den += dpin[src];
            }
        }
    }
    float mean = (den > 0.f) ? acc / den : 0.f;   // ||mean|| <= 1
    float p = mean * mean;
#pragma unroll
    for (int k = 16; k >= 1; k >>= 1) p += __shfl_xor(p, k);
    return (p > 0.f) ? mean * (1.0f / sqrtf(p)) : 0.f;
}

// ---------------------------------------------------------------------------
// prep_init: one block per (b, 16x16 pixel block).
//  - per-pixel L2-normalize x along channels -> xn[b][y][x][c] (channel-last)
//  - raw block mean over the 16x16 block, L2-normalized -> clst0[b][cell][c]
// ---------------------------------------------------------------------------
__global__ __launch_bounds__(256) void prep_init_kernel(const float* __restrict__ x,
                                                        float* __restrict__ xn,
                                                        float* __restrict__ clst0) {
    int blk = blockIdx.x;          // b*256 + cell
    int b = blk >> 8;
    int cell = blk & 255;
    int ci = cell >> 4, cj = cell & 15;
    int t = threadIdx.x;
    int py = t >> 4, px = t & 15;
    int y = ci * 16 + py, xx = cj * 16 + px;
    int rem = y * 256 + xx;

    __shared__ float sraw[256 * 33];   // padded stride 33
    __shared__ float red[256];

    const float* xb = x + (size_t)b * (32 * 65536);
    float v[32];
    float ss = 0.f;
#pragma unroll
    for (int c = 0; c < 32; ++c) {
        float tv = xb[c * 65536 + rem];
        v[c] = tv;
        ss += tv * tv;
        sraw[t * 33 + c] = tv;
    }
    float rn = 1.0f / sqrtf(ss);
    float4* outp = (float4*)(xn + ((size_t)b * 65536 + rem) * 32);
#pragma unroll
    for (int q = 0; q < 8; ++q)
        outp[q] = make_float4(v[4*q]*rn, v[4*q+1]*rn, v[4*q+2]*rn, v[4*q+3]*rn);

    __syncthreads();
    int c = t & 31, pg = t >> 5;
    float acc = 0.f;
#pragma unroll
    for (int k = 0; k < 32; ++k) acc += sraw[(pg * 32 + k) * 33 + c];
    red[t] = acc;
    __syncthreads();
    if (t < 128) red[t] += red[t + 128];
    __syncthreads();
    if (t < 64) red[t] += red[t + 64];
    __syncthreads();
    if (t < 32) {
        float m = (red[t] + red[t + 32]) * (1.0f / 256.0f);
        float p = m * m;
#pragma unroll
        for (int k = 16; k >= 1; k >>= 1) p += __shfl_xor(p, k);
        clst0[(size_t)blk * 32 + t] = m * (1.0f / sqrtf(p));
    }
}

// ---------------------------------------------------------------------------
// accum9c: one block per (b, pixel-block). Head: build the 9 neighbor clusters
// either from clst0 (it==0) or by redundant deterministic combine of the
// previous iteration's partials (it>=1). Body: e_q(p)=exp((dot-0.5)/tau);
// partials Sout[blk][q][c]=sum e*x, dpout[blk][q]=sum e. Pixels are staged in
// LDS once (sx) so the accumulation phase reads LDS, not global.
// At it==4 also stores own-cell cluster (iter-5 input).
// ---------------------------------------------------------------------------
__global__ __launch_bounds__(256) void accum9c_kernel(const float* __restrict__ xn,
                                                      const float* __restrict__ clst0,
                                                      const float* __restrict__ Sin,
                                                      const float* __restrict__ dpin,
                                                      float* __restrict__ Sout,
                                                      float* __restrict__ dpout,
                                                      float* __restrict__ clstin5,
                                                      int it) {
    int blk = blockIdx.x;           // b*256 + block
    int b = blk >> 8;
    int cell = blk & 255;
    int bi = cell >> 4, bj = cell & 15;
    int t = threadIdx.x;

    __shared__ float sx[256 * 33];  // this block's 256 pixel features
    __shared__ float sclst[9][32];
    __shared__ float se[9][256];
    __shared__ float sacc[8][9][32];
    __shared__ float sdw[4][9];

    if (it == 0) {
        for (int u = t; u < 288; u += 256) {
            int q = u >> 5, c = u & 31;
            int ii = bi + q / 3 - 1, jj = bj + q % 3 - 1;
            float v = 0.f;
            if (ii >= 0 && ii < 16 && jj >= 0 && jj < 16)
                v = clst0[((size_t)(b * 256 + ii * 16 + jj)) * 32 + c];
            sclst[q][c] = v;
        }
    } else {
        {
            int q = t >> 5, c = t & 31;              // q = 0..7
            float v = combine_one(Sin, dpin, b, bi + q / 3 - 1, bj + q % 3 - 1, c);
            sclst[q][c] = v;
            if (it == 4 && q == 4)                   // own cell = iter-5 input clst
                clstin5[(size_t)blk * 32 + c] = v;
        }
        if (t < 32)                                  // q = 8 -> offset (1,1)
            sclst[8][t] = combine_one(Sin, dpin, b, bi + 1, bj + 1, t);
    }

    int y = bi * 16 + (t >> 4), xx = bj * 16 + (t & 15);
    const float4* f4 = (const float4*)(xn + ((size_t)(b * 65536 + y * 256 + xx)) * 32);
    float fv[32];
#pragma unroll
    for (int q = 0; q < 8; ++q) {
        float4 v = f4[q];
        fv[4*q] = v.x; fv[4*q+1] = v.y; fv[4*q+2] = v.z; fv[4*q+3] = v.w;
    }
#pragma unroll
    for (int c = 0; c < 32; ++c) sx[t * 33 + c] = fv[c];
    __syncthreads();                // sclst + sx both ready

    int wid = t >> 6, lane = t & 63;
#pragma unroll
    for (int q = 0; q < 9; ++q) {
        float s = 0.f;
#pragma unroll
        for (int c = 0; c < 32; ++c) s += fv[c] * sclst[q][c];
        // s==0 <=> OOB target (sclst=0) or exact-zero dot; reference masks both.
        float ev = (s == 0.f) ? 0.f : SHIFTED_EXP(s);
        se[q][t] = ev;
        float d = ev;
#pragma unroll
        for (int k = 32; k >= 1; k >>= 1) d += __shfl_xor(d, k);
        if (lane == 0) sdw[wid][q] = d;
    }
    __syncthreads();
    if (t < 9) dpout[blk * 9 + t] = sdw[0][t] + sdw[1][t] + sdw[2][t] + sdw[3][t];

    // accumulation: thread = (c = t&31, pg = t>>5), 32 pixels each, 9 targets.
    // All operands in LDS.
    {
        int c = t & 31, pg = t >> 5;
        float acc[9];
#pragma unroll
        for (int q = 0; q < 9; ++q) acc[q] = 0.f;
#pragma unroll
        for (int k = 0; k < 32; ++k) {
            int p = pg * 32 + k;
            float xv = sx[p * 33 + c];
#pragma unroll
            for (int q = 0; q < 9; ++q) acc[q] = fmaf(se[q][p], xv, acc[q]);
        }
#pragma unroll
        for (int q = 0; q < 9; ++q) sacc[pg][q][c] = acc[q];
    }
    __syncthreads();

    {
        int q = t >> 5, cc = t & 31;   // q 0..7
        float s8 = 0.f;
#pragma unroll
        for (int g = 0; g < 8; ++g) s8 += sacc[g][q][cc];
        Sout[((size_t)blk * 9 + q) * 32 + cc] = s8;
        if (t < 32) {
            float s9 = 0.f;
#pragma unroll
            for (int g = 0; g < 8; ++g) s9 += sacc[g][8][t];
            Sout[((size_t)blk * 9 + 8) * 32 + t] = s9;
        }
    }
}

// ---------------------------------------------------------------------------
// tail: one block per (b, (ky0,kx0) lattice residue / pixel-block).
// Phase A (s2p): stage the 16x16 lattice of pixels {(16r+ky0, 16s+kx0)} in LDS
// plus the full clstin5 table; each thread t = target cell computes the 9
// window positions p=(ky0+16a)*48+kx0+16b -- every s2p element written exactly
// once, coalesced, with each pixel fetched from global exactly once per batch.
// Phase B (p2s): pixel-block (ky0,kx0), hood clusters from redundant combine.
// Also writes the final clst output (own cell).
// ---------------------------------------------------------------------------
__global__ __launch_bounds__(256) void tail_kernel(const float* __restrict__ xn,
                                                   const float* __restrict__ Sin,
                                                   const float* __restrict__ dpin,
                                                   const float* __restrict__ clstin5,
                                                   float* __restrict__ out_clst,
                                                   float* __restrict__ out_p2s,
                                                   float* __restrict__ out_s2p) {
    int blk = blockIdx.x;
    int b = blk >> 8;
    int cell = blk & 255;
    int ky0 = cell >> 4, kx0 = cell & 15;   // lattice residue == pixel-block id
    int t = threadIdx.x;

    __shared__ float sx[256 * 33];   // clstin5 table (s2p)
    __shared__ float L[256 * 33];    // lattice pixel features (s2p)
    __shared__ float sclst[9][32];   // final clst of 3x3 hood (p2s)
    __shared__ float srd[256];       // 1/den per target cell (s2p)

    // final combine hood (for p2s) + own-cell clst output
    {
        int q = t >> 5, c = t & 31;              // q = 0..7
        float v = combine_one(Sin, dpin, b, ky0 + q / 3 - 1, kx0 + q % 3 - 1, c);
        sclst[q][c] = v;
        if (q == 4)
            out_clst[((size_t)b * 32 + c) * 256 + cell] = v;
    }
    if (t < 32)
        sclst[8][t] = combine_one(Sin, dpin, b, ky0 + 1, kx0 + 1, t);

    // stage clstin5 table
    for (int u = t; u < 8192; u += 256)
        sx[(u >> 5) * 33 + (u & 31)] = clstin5[(size_t)b * 8192 + u];

    // stage lattice pixels: thread t = (r,s) -> pixel (16r+ky0, 16s+kx0)
    {
        int r = t >> 4, s = t & 15;
        const float4* f4 = (const float4*)(xn +
            ((size_t)(b * 65536 + (16 * r + ky0) * 256 + 16 * s + kx0)) * 32);
#pragma unroll
        for (int q = 0; q < 8; ++q) {
            float4 v = f4[q];
            L[t * 33 + 4*q]     = v.x;
            L[t * 33 + 4*q + 1] = v.y;
            L[t * 33 + 4*q + 2] = v.z;
            L[t * 33 + 4*q + 3] = v.w;
        }
    }

    {   // den of iteration 5 per target cell t
        int i = t >> 4, j = t & 15;
        float den = 0.f;
#pragma unroll
        for (int u = 0; u < 9; ++u) {
            int oy = u / 3 - 1, ox = u % 3 - 1;
            int ii = i + oy, jj = j + ox;
            if (ii >= 0 && ii < 16 && jj >= 0 && jj < 16)
                den += dpin[((b * 256 + ii * 16 + jj) * 9) + (1 - oy) * 3 + (1 - ox)];
        }
        srd[t] = 1.0f / den;                     // den > 0 always (valid cell)
    }
    __syncthreads();

    // s2p: thread t = target cell (i,j); 9 positions (a,bb)
    {
        int i = t >> 4, j = t & 15;
        const float* cl = sx + t * 33;
        float rd = srd[t];
#pragma unroll
        for (int a = 0; a < 3; ++a) {
#pragma unroll
            for (int bb = 0; bb < 3; ++bb) {
                int r = i + a - 1, s2 = j + bb - 1;   // lattice coords of pixel
                float val = 0.f;
                if (r >= 0 && r < 16 && s2 >= 0 && s2 < 16) {
                    const float* f = L + (r * 16 + s2) * 33;
                    float s = 0.f;
#pragma unroll
                    for (int c = 0; c < 32; ++c) s += f[c] * cl[c];
                    if (s != 0.f) val = SHIFTED_EXP(s) * rd;
                }
                int p = (ky0 + 16 * a) * 48 + kx0 + 16 * bb;
                out_s2p[(size_t)(b * 2304 + p) * 256 + t] = val;
            }
        }
    }

    // p2s for own pixel-block (ky0,kx0)
    {
        int py = t >> 4, px = t & 15;
        int rem = (ky0 * 16 + py) * 256 + kx0 * 16 + px;
        const float4* f4 = (const float4*)(xn + ((size_t)b * 65536 + rem) * 32);
        float fv[32];
#pragma unroll
        for (int q = 0; q < 8; ++q) {
            float4 v = f4[q];
            fv[4*q] = v.x; fv[4*q+1] = v.y; fv[4*q+2] = v.z; fv[4*q+3] = v.w;
        }
        float l[9];
        float mx = -INFINITY;
#pragma unroll
        for (int q = 0; q < 9; ++q) {
            float s = 0.f;
#pragma unroll
            for (int c = 0; c < 32; ++c) s += fv[c] * sclst[q][c];
            l[q] = (s == 0.f) ? -INFINITY : s * TAU_INV;
            mx = fmaxf(mx, l[q]);
        }
        float e[9], sum = 0.f;
#pragma unroll
        for (int q = 0; q < 9; ++q) {
            e[q] = (l[q] == -INFINITY) ? 0.f : expf(l[q] - mx);
            sum += e[q];
        }
        float rs = 1.0f / sum;
#pragma unroll
        for (int q = 0; q < 9; ++q)
            out_p2s[((size_t)b * 9 + q) * 65536 + rem] = e[q] * rs;
    }
}

extern "C" void kernel_launch(void* const* d_in, const int* in_sizes, int n_in,
                              void* d_out, int out_size, void* d_ws, size_t ws_size,
                              hipStream_t stream) {
    const float* x = (const float*)d_in[0];
    float* out = (float*)d_out;

    float* out_clst = out;                       // 2*32*16*16      = 16384
    float* out_p2s  = out + 16384;               // 2*9*256*256     = 1179648
    float* out_s2p  = out + 16384 + 1179648;     // 2*2304*16*16    = 1179648

    float* ws = (float*)d_ws;
    float* xn      = ws;                         // 4,194,304
    float* clst0   = xn + 4194304;               // 16,384
    float* Sa      = clst0 + 16384;              // 147,456
    float* Sb      = Sa + 147456;                // 147,456
    float* dpa     = Sb + 147456;                // 4,608
    float* dpb     = dpa + 4608;                 // 4,608
    float* clstin5 = dpb + 4608;                 // 16,384
    // total ~18.1 MB << ws_size

    prep_init_kernel<<<512, 256, 0, stream>>>(x, xn, clst0);

    // it0 reads clst0 (Sin/dpin unread), writes B; then alternate.
    float* Sin = Sa;  float* dpin = dpa;
    float* Sout = Sb; float* dpout = dpb;
    for (int it = 0; it < 5; ++it) {
        accum9c_kernel<<<512, 256, 0, stream>>>(xn, clst0, Sin, dpin,
                                                Sout, dpout, clstin5, it);
        float* ts = Sin; Sin = Sout; Sout = ts;
        float* td = dpin; dpin = dpout; dpout = td;
    }
    // Sin/dpin now hold S5/dp5
    tail_kernel<<<512, 256, 0, stream>>>(xn, Sin, dpin, clstin5,
                                         out_clst, out_p2s, out_s2p);
}